// Round 1
// baseline (18178.456 us; speedup 1.0000x reference)
//
#include <hip/hip_runtime.h>

#define HID 128
typedef long long i64;

__device__ inline void fma4(float4& a, const float4& w, float s) {
  a.x = fmaf(w.x, s, a.x); a.y = fmaf(w.y, s, a.y);
  a.z = fmaf(w.z, s, a.z); a.w = fmaf(w.w, s, a.w);
}

enum { M_XS = 0, M_XWE = 1, M_EDGEOUT = 2, M_XWN = 3, M_FINAL = 4 };

// out[r,:] = in[r,:] @ Wa (+ mode-specific epilogue). W staged in LDS (64KB).
// Thread layout: 256 threads; slot=tid>>1 (128 slots), ch=tid&1 (col half).
// Rows r0=base+slot, r1=base+128+slot; cols ch*64..ch*64+63. 128 f32 acc/thread.
template<int MODE>
__global__ __launch_bounds__(256)
void gemm128(const float* __restrict__ in, const float* __restrict__ in2,
             const float* __restrict__ Wa, const float* __restrict__ Wb,
             const float* __restrict__ bias, const float* __restrict__ resid,
             const float* __restrict__ gA, const float* __restrict__ gB,
             const int* __restrict__ send, const int* __restrict__ recv,
             float* __restrict__ out, float* __restrict__ agg, int R)
{
  __shared__ float wlds[HID * HID]; // 64 KiB
  const int tid = threadIdx.x;
  const int slot = tid >> 1, ch = tid & 1;
  const int base = blockIdx.x * 256;
  const int r0 = base + slot, r1 = base + 128 + slot;
  const bool v0 = r0 < R, v1 = r1 < R;
  const int rc0 = v0 ? r0 : 0, rc1 = v1 ? r1 : 0; // clamped for safe loads

  float4 acc0[16], acc1[16];
#pragma unroll
  for (int j = 0; j < 16; ++j) {
    acc0[j] = make_float4(0.f, 0.f, 0.f, 0.f);
    acc1[j] = make_float4(0.f, 0.f, 0.f, 0.f);
  }

  auto stageW = [&](const float* W) {
    const float4* W4 = (const float4*)W;
    float4* L4 = (float4*)wlds;
#pragma unroll
    for (int i = 0; i < 16; ++i) L4[tid + i * 256] = W4[tid + i * 256];
  };

  auto accum = [&](const float* src) {
    const float4* a0p = (const float4*)(src + (i64)rc0 * HID);
    const float4* a1p = (const float4*)(src + (i64)rc1 * HID);
    for (int k4 = 0; k4 < 32; ++k4) {
      float4 a0 = a0p[k4];
      float4 a1 = a1p[k4];
      float s0[4] = {a0.x, a0.y, a0.z, a0.w};
      float s1[4] = {a1.x, a1.y, a1.z, a1.w};
#pragma unroll
      for (int kk = 0; kk < 4; ++kk) {
        const float4* wr = (const float4*)(wlds + (k4 * 4 + kk) * HID + ch * 64);
#pragma unroll
        for (int j = 0; j < 16; ++j) {
          float4 w = wr[j];
          fma4(acc0[j], w, s0[kk]);
          fma4(acc1[j], w, s1[kk]);
        }
      }
    }
  };

  stageW(Wa);
  __syncthreads();
  accum(in);
  if constexpr (MODE == M_XWN) {
    __syncthreads();
    stageW(Wb);
    __syncthreads();
    accum(in2);
  }

  const int c0 = ch * 64;

  auto writeRow = [&](int r, bool v, float4* acc) {
    if (!v) return;
    const i64 ro = (i64)r * HID + c0;
    if constexpr (MODE == M_XS || MODE == M_XWN) {
      float4* o = (float4*)(out + ro);
#pragma unroll
      for (int j = 0; j < 16; ++j) o[j] = acc[j];
    } else if constexpr (MODE == M_XWE) {
      const int s = send[r], c = recv[r];
      const float4* pa = (const float4*)(gA + (i64)s * HID + c0);
      const float4* pb = (const float4*)(gB + (i64)c * HID + c0);
      float4* o = (float4*)(out + ro);
#pragma unroll
      for (int j = 0; j < 16; ++j) {
        float4 v4 = acc[j]; float4 a = pa[j]; float4 b = pb[j];
        v4.x += a.x + b.x; v4.y += a.y + b.y;
        v4.z += a.z + b.z; v4.w += a.w + b.w;
        o[j] = v4;
      }
    } else if constexpr (MODE == M_EDGEOUT) {
      const int c = recv[r];
      const float4* bi = (const float4*)(bias + c0);
      const float4* rs = (const float4*)(resid + ro);
      float4* o = (float4*)(out + ro);
      float* ag = agg + (i64)c * HID + c0;
#pragma unroll
      for (int j = 0; j < 16; ++j) {
        float4 ne = acc[j]; float4 b = bi[j]; float4 rr = rs[j];
        ne.x += b.x; ne.y += b.y; ne.z += b.z; ne.w += b.w;
        atomicAdd(ag + j * 4 + 0, ne.x);
        atomicAdd(ag + j * 4 + 1, ne.y);
        atomicAdd(ag + j * 4 + 2, ne.z);
        atomicAdd(ag + j * 4 + 3, ne.w);
        float4 ov;
        ov.x = rr.x + ne.x; ov.y = rr.y + ne.y;
        ov.z = rr.z + ne.z; ov.w = rr.w + ne.w;
        o[j] = ov;
      }
    } else { // M_FINAL
      const float4* bi = (const float4*)(bias + c0);
      const float4* rs = (const float4*)(resid + ro);
      float4* o = (float4*)(out + ro);
#pragma unroll
      for (int j = 0; j < 16; ++j) {
        float4 ne = acc[j]; float4 b = bi[j]; float4 rr = rs[j];
        ne.x += b.x + rr.x; ne.y += b.y + rr.y;
        ne.z += b.z + rr.z; ne.w += b.w + rr.w;
        o[j] = ne;
      }
    }
  };
  writeRow(r0, v0, acc0);
  writeRow(r1, v1, acc1);
}

__global__ __launch_bounds__(256)
void count_recv(const int* __restrict__ recv, int* __restrict__ indeg, int E) {
  int i = blockIdx.x * 256 + threadIdx.x;
  if (i < E) atomicAdd(&indeg[recv[i]], 1);
}

__global__ __launch_bounds__(256)
void calc_dinv(const int* __restrict__ indeg, float* __restrict__ dinv, int N) {
  int i = blockIdx.x * 256 + threadIdx.x;
  if (i < N) dinv[i] = rsqrtf((float)indeg[i] + 1.0f);
}

// S[c,:] += dinv[s]*dinv[c] * xw[s,:]  for each edge (s=send, c=recv); c,s < N.
__global__ __launch_bounds__(256)
void scatter_norm(const float* __restrict__ xw, const float* __restrict__ dinv,
                  const int* __restrict__ send, const int* __restrict__ recv,
                  float* __restrict__ S, int E)
{
  i64 j = (i64)blockIdx.x * 256 + threadIdx.x;
  if (j >= (i64)E * 4) return;
  int e = (int)(j >> 2), q = (int)(j & 3);
  int s = send[e], c = recv[e];
  float coef = dinv[s] * dinv[c];
  const float4* src = (const float4*)(xw + (i64)s * HID + q * 32);
  float* dst = S + (i64)c * HID + q * 32;
#pragma unroll
  for (int i = 0; i < 8; ++i) {
    float4 v = src[i];
    atomicAdd(dst + i * 4 + 0, coef * v.x);
    atomicAdd(dst + i * 4 + 1, coef * v.y);
    atomicAdd(dst + i * 4 + 2, coef * v.z);
    atomicAdd(dst + i * 4 + 3, coef * v.w);
  }
}

// in-place: h[i,:] = relu(xw[i,:] * dinv_e[i]^2 + (i<N ? S[i,:] : 0) + bias)
__global__ __launch_bounds__(256)
void h_edge(float* __restrict__ xw, const float* __restrict__ S,
            const float* __restrict__ dinv, const float* __restrict__ bias,
            int N, i64 E)
{
  i64 j = (i64)blockIdx.x * 256 + threadIdx.x; // one float4 each
  if (j >= E * 32) return;
  i64 row = j >> 5; int q = (int)(j & 31);
  bool hasS = row < (i64)N;
  float d = hasS ? dinv[row] : 1.0f;
  float d2 = d * d;
  float m = hasS ? 1.0f : 0.0f;
  i64 rs = hasS ? row : 0;
  float4 v = ((const float4*)xw)[j];
  float4 sv = ((const float4*)S)[rs * 32 + q];
  float4 b = ((const float4*)bias)[q];
  v.x = fmaxf(fmaf(v.x, d2, sv.x * m + b.x), 0.f);
  v.y = fmaxf(fmaf(v.y, d2, sv.y * m + b.y), 0.f);
  v.z = fmaxf(fmaf(v.z, d2, sv.z * m + b.z), 0.f);
  v.w = fmaxf(fmaf(v.w, d2, sv.w * m + b.w), 0.f);
  ((float4*)xw)[j] = v;
}

__global__ __launch_bounds__(256)
void h_node(float* __restrict__ xw, const float* __restrict__ S,
            const float* __restrict__ dinv, const float* __restrict__ bias,
            int N)
{
  i64 j = (i64)blockIdx.x * 256 + threadIdx.x;
  if (j >= (i64)N * 32) return;
  i64 row = j >> 5; int q = (int)(j & 31);
  float d = dinv[row];
  float d2 = d * d;
  float4 v = ((const float4*)xw)[j];
  float4 sv = ((const float4*)S)[j];
  float4 b = ((const float4*)bias)[q];
  v.x = fmaxf(fmaf(v.x, d2, sv.x + b.x), 0.f);
  v.y = fmaxf(fmaf(v.y, d2, sv.y + b.y), 0.f);
  v.z = fmaxf(fmaf(v.z, d2, sv.z + b.z), 0.f);
  v.w = fmaxf(fmaf(v.w, d2, sv.w + b.w), 0.f);
  ((float4*)xw)[j] = v;
}

extern "C" void kernel_launch(void* const* d_in, const int* in_sizes, int n_in,
                              void* d_out, int out_size, void* d_ws, size_t ws_size,
                              hipStream_t stream)
{
  const float* x        = (const float*)d_in[0];
  const float* ea       = (const float*)d_in[1];
  const int*   eidx     = (const int*)d_in[2];
  const float* W_eb     = (const float*)d_in[3];
  const float* b_ebg    = (const float*)d_in[4];
  const float* W_eb_out = (const float*)d_in[5];
  const float* b_ebo    = (const float*)d_in[6];
  const float* W_nb     = (const float*)d_in[7];
  const float* b_nbg    = (const float*)d_in[8];
  const float* W_nb_out = (const float*)d_in[9];
  const float* b_nbo    = (const float*)d_in[10];

  const int N = in_sizes[0] / HID;
  const int E = in_sizes[1] / HID;
  const int* send = eidx;
  const int* recv = eidx + E;

  char* wsb = (char*)d_ws;
  int*   indeg = (int*)wsb;
  float* dinv  = (float*)(wsb + (1u << 20));
  size_t bsz = (size_t)N * HID * sizeof(float);
  float* bufA = (float*)(wsb + 2 * (1u << 20));
  float* bufB = (float*)((char*)bufA + bsz);
  float* bufC = (float*)((char*)bufB + bsz);

  float* outX = (float*)d_out;              // [N,128] new_x residual output
  float* outE = outX + (size_t)N * HID;     // [E,128] new_edge residual output (also scratch)

  const float* W1  = W_eb;                  // x[senders] block
  const float* W2  = W_eb + 128 * HID;      // x[receivers] block
  const float* W3  = W_eb + 256 * HID;      // edge_attr block
  const float* Wn1 = W_nb;                  // x block
  const float* Wn2 = W_nb + 128 * HID;      // agg block

  const int gN = (N + 255) / 256;
  const int gE = (E + 255) / 256;

  // degrees (shared by both GCNs on indices < N)
  hipMemsetAsync(indeg, 0, (size_t)N * sizeof(int), stream);
  count_recv<<<(E + 255) / 256, 256, 0, stream>>>(recv, indeg, E);
  calc_dinv<<<(N + 255) / 256, 256, 0, stream>>>(indeg, dinv, N);

  // xsA = x@W1, xsB = x@W2
  gemm128<M_XS><<<gN, 256, 0, stream>>>(x, nullptr, W1, nullptr, nullptr, nullptr,
                                        nullptr, nullptr, nullptr, nullptr, bufA, nullptr, N);
  gemm128<M_XS><<<gN, 256, 0, stream>>>(x, nullptr, W2, nullptr, nullptr, nullptr,
                                        nullptr, nullptr, nullptr, nullptr, bufB, nullptr, N);

  // xw_e = ea@W3 + xsA[send] + xsB[recv]  -> outE (scratch use of d_out)
  gemm128<M_XWE><<<gE, 256, 0, stream>>>(ea, nullptr, W3, nullptr, nullptr, nullptr,
                                         bufA, bufB, send, recv, outE, nullptr, E);

  // S_head = scatter of dinv[s]*dinv[c]*xw_e[s] into rows c  (bufA reused)
  hipMemsetAsync(bufA, 0, bsz, stream);
  scatter_norm<<<(int)(((i64)E * 4 + 255) / 256), 256, 0, stream>>>(outE, dinv, send, recv, bufA, E);

  // h_e = relu(dinv_e^2*xw_e + S + b)  in-place on outE
  h_edge<<<(int)(((i64)E * 32 + 255) / 256), 256, 0, stream>>>(outE, bufA, dinv, b_ebg, N, (i64)E);

  // new_edge = h_e@W_eb_out + b; outE = ea + new_edge (in-place); agg += new_edge (bufB reused)
  hipMemsetAsync(bufB, 0, bsz, stream);
  gemm128<M_EDGEOUT><<<gE, 256, 0, stream>>>(outE, nullptr, W_eb_out, nullptr, b_ebo, ea,
                                             nullptr, nullptr, send, recv, outE, bufB, E);

  // xw_n = x@Wn1 + agg@Wn2 -> bufC
  gemm128<M_XWN><<<gN, 256, 0, stream>>>(x, bufB, Wn1, Wn2, nullptr, nullptr,
                                         nullptr, nullptr, nullptr, nullptr, bufC, nullptr, N);

  // S_n scatter (bufA reused)
  hipMemsetAsync(bufA, 0, bsz, stream);
  scatter_norm<<<(int)(((i64)E * 4 + 255) / 256), 256, 0, stream>>>(bufC, dinv, send, recv, bufA, E);

  // h_n = relu(dinv^2*xw_n + S_n + b) in-place on bufC
  h_node<<<(int)(((i64)N * 32 + 255) / 256), 256, 0, stream>>>(bufC, bufA, dinv, b_nbg, N);

  // new_x = h_n@W_nb_out + b; outX = x + new_x
  gemm128<M_FINAL><<<gN, 256, 0, stream>>>(bufC, nullptr, W_nb_out, nullptr, b_nbo, x,
                                           nullptr, nullptr, nullptr, nullptr, outX, nullptr, N);
}